// Round 3
// baseline (108.574 us; speedup 1.0000x reference)
//
#include <hip/hip_runtime.h>
#include <hip/hip_bf16.h>
#include <stdint.h>

// MoEDecoder: B=64,T=256,IN=256,HID=512,OUT=256,L=2,E=16,S=1
// Whole chain is row-local (no cross-token deps) => single fused persistent
// kernel: block = 64-token slab (grid 256 = 1 block/CU), h lives in LDS
// (ping-pong padded buffers), weights staged per-K-step via global_load_lds.
// Pre-pass: bf16 weight conversion + Wc[l,e]=Ws[l,0]+Wr[l,e] pre-sum.

typedef __attribute__((ext_vector_type(8))) short bf16x8;
typedef __attribute__((ext_vector_type(4))) float f32x4;

#define HPAD 520  // h row stride in elems (pad 512+8 to spread banks)

static __device__ __forceinline__ uint16_t f2bf(float f) {
  union { float f; uint32_t u; } c; c.f = f;
  uint32_t r = (c.u + 0x7FFFu + ((c.u >> 16) & 1u)) >> 16;
  return (uint16_t)r;
}
static __device__ __forceinline__ float bf2f(uint16_t h) {
  union { uint32_t u; float f; } c; c.u = ((uint32_t)h) << 16;
  return c.f;
}

static __device__ __forceinline__ void glds16(const uint16_t* g, uint16_t* l) {
  __builtin_amdgcn_global_load_lds(
      (const __attribute__((address_space(1))) uint32_t*)g,
      (__attribute__((address_space(3))) uint32_t*)l, 16, 0, 0);
}

__global__ __launch_bounds__(256) void k_f32_to_bf16(
    const float* __restrict__ in, uint16_t* __restrict__ out, int n4) {
  int i = blockIdx.x * 256 + threadIdx.x;
  if (i < n4) {
    float4 v = ((const float4*)in)[i];
    ushort4 o;
    o.x = f2bf(v.x); o.y = f2bf(v.y); o.z = f2bf(v.z); o.w = f2bf(v.w);
    ((ushort4*)out)[i] = o;
  }
}

// Wc[l,e,:,:] = Ws[l,0,:,:] + Wr[l,e,:,:]  (bf16 out)
__global__ __launch_bounds__(256) void k_combine_w(
    const float* __restrict__ Ws, const float* __restrict__ Wr,
    uint16_t* __restrict__ Wc, int n4) {
  int i = blockIdx.x * 256 + threadIdx.x;
  if (i >= n4) return;
  int idx = i * 4;
  int l = idx >> 22;
  int within = idx & (262144 - 1);
  float4 a = *(const float4*)(Ws + l * 262144 + within);
  float4 b = *(const float4*)(Wr + idx);
  ushort4 o;
  o.x = f2bf(a.x + b.x); o.y = f2bf(a.y + b.y);
  o.z = f2bf(a.z + b.z); o.w = f2bf(a.w + b.w);
  ((ushort4*)Wc)[i] = o;
}

// bc[l,e,n] = bs[l,0,n] + br[l,e,n]
__global__ __launch_bounds__(256) void k_combine_b(
    const float* __restrict__ bs, const float* __restrict__ br,
    float* __restrict__ bc, int n) {
  int i = blockIdx.x * 256 + threadIdx.x;
  if (i < n) {
    int l = i >> 13;
    int j = i & 511;
    bc[i] = bs[l * 512 + j] + br[i];
  }
}

// ---------------- fused chain kernel ----------------
// 4 waves in 2x2; wave tile = 32 rows x 64 cols per 128-col chunk.
// One GEMM phase: C[64][N] = inL[64][K] * W[N][K]^T (+bias)(+resid)(relu)
template <int RELU, int RESID, int F32OUT>
static __device__ __forceinline__ void gemm_phase(
    const uint16_t* __restrict__ W, const float* __restrict__ bias,
    const uint16_t* inL, uint16_t* outL, float* __restrict__ gout,
    uint16_t* lB, int N, int K) {
  int tid = threadIdx.x;
  int wave = tid >> 6, lane = tid & 63;
  int wr = wave >> 1, wc = wave & 1;
  int lr = lane & 15, lk = (lane >> 4) * 8, rb = (lane >> 4) * 4;
  int srow = tid >> 2, scol = (tid & 3) * 8;

  for (int nc = 0; nc < N; nc += 128) {
    f32x4 acc[2][4];
    #pragma unroll
    for (int m = 0; m < 2; m++)
      #pragma unroll
      for (int n = 0; n < 4; n++) acc[m][n] = (f32x4){0.f, 0.f, 0.f, 0.f};

    const uint16_t* gB = W + (size_t)(nc + srow) * K + scol;

    for (int k0 = 0; k0 < K; k0 += 32) {
      glds16(gB + k0, lB + tid * 8);
      glds16(gB + (size_t)64 * K + k0, lB + 2048 + tid * 8);
      __syncthreads();  // stage done (also guards prev epilogue/outL writes)

      bf16x8 a[2], b[4];
      #pragma unroll
      for (int m = 0; m < 2; m++)
        a[m] = *(const bf16x8*)(inL + (size_t)(wr * 32 + m * 16 + lr) * HPAD + k0 + lk);
      #pragma unroll
      for (int n = 0; n < 4; n++)
        b[n] = *(const bf16x8*)(lB + (size_t)(wc * 64 + n * 16 + lr) * 32 + lk);
      #pragma unroll
      for (int m = 0; m < 2; m++)
        #pragma unroll
        for (int n = 0; n < 4; n++)
          acc[m][n] = __builtin_amdgcn_mfma_f32_16x16x32_bf16(a[m], b[n],
                                                              acc[m][n], 0, 0, 0);
      __syncthreads();  // compute done before restage
    }

    // epilogue: D col=lane&15, row=(lane>>4)*4+r per 16x16 frag
    #pragma unroll
    for (int n = 0; n < 4; n++) {
      int col = nc + wc * 64 + n * 16 + lr;
      float bv = bias[col];
      #pragma unroll
      for (int m = 0; m < 2; m++) {
        #pragma unroll
        for (int r = 0; r < 4; r++) {
          int row = wr * 32 + m * 16 + rb + r;
          float v = acc[m][n][r] + bv;
          if (RESID) v += bf2f(inL[(size_t)row * HPAD + col]);
          if (RELU) v = fmaxf(v, 0.0f);
          if (F32OUT) gout[(size_t)row * N + col] = v;
          else outL[(size_t)row * HPAD + col] = f2bf(v);
        }
      }
    }
  }
}

__global__ __launch_bounds__(256) void k_fused(
    const float* __restrict__ x, const int* __restrict__ route,
    const uint16_t* __restrict__ Wib, const float* __restrict__ bi,
    const uint16_t* __restrict__ Wcb, const float* __restrict__ bcb,
    const uint16_t* __restrict__ Wob, const float* __restrict__ bo,
    float* __restrict__ out) {
  __shared__ uint16_t hA[64 * HPAD];   // 66,560 B
  __shared__ uint16_t hB[64 * HPAD];   // 66,560 B
  __shared__ uint16_t lB[4096];        //  8,192 B  (B-tile stage)
  // total 141,312 B -> 1 block/CU

  int tid = threadIdx.x;
  int bx = blockIdx.x;                 // 64-row slab
  int e = route[bx >> 2];              // 256 rows per batch

  // ---- stage x slab: f32 -> bf16 into hA (coalesced, 4KB/iter) ----
  const float* gx = x + (size_t)bx * 64 * 256;
  #pragma unroll 4
  for (int j = 0; j < 16; j++) {
    int idx = j * 1024 + tid * 4;
    float4 v = *(const float4*)(gx + idx);
    int row = idx >> 8, c = idx & 255;
    ushort4 o;
    o.x = f2bf(v.x); o.y = f2bf(v.y); o.z = f2bf(v.z); o.w = f2bf(v.w);
    *(ushort4*)(hA + (size_t)row * HPAD + c) = o;
  }
  __syncthreads();

  // ---- proj: hB = relu(hA * Wi^T + bi)   N=512 K=256 ----
  gemm_phase<1, 0, 0>(Wib, bi, hA, hB, nullptr, lB, 512, 256);
  __syncthreads();
  // ---- layer 0: hA = relu(hB * Wc[0,e]^T + bc[0,e] + hB)  N=K=512 ----
  gemm_phase<1, 1, 0>(Wcb + (size_t)e * 262144, bcb + e * 512,
                      hB, hA, nullptr, lB, 512, 512);
  __syncthreads();
  // ---- layer 1: hB = relu(hA * Wc[1,e]^T + bc[1,e] + hA) ----
  gemm_phase<1, 1, 0>(Wcb + (size_t)(16 + e) * 262144, bcb + (16 + e) * 512,
                      hA, hB, nullptr, lB, 512, 512);
  __syncthreads();
  // ---- out: f32 global = hB * Wo^T + bo   N=256 K=512 ----
  gemm_phase<0, 0, 1>(Wob, bo, hB, nullptr, out + (size_t)bx * 64 * 256,
                      lB, 256, 512);
}

extern "C" void kernel_launch(void* const* d_in, const int* in_sizes, int n_in,
                              void* d_out, int out_size, void* d_ws, size_t ws_size,
                              hipStream_t stream) {
  const float* x     = (const float*)d_in[0];
  const int*   route = (const int*)d_in[1];
  const float* Wi    = (const float*)d_in[2];
  const float* bi    = (const float*)d_in[3];
  const float* Wr    = (const float*)d_in[4];
  const float* br    = (const float*)d_in[5];
  const float* Ws    = (const float*)d_in[6];
  const float* bs    = (const float*)d_in[7];
  const float* Wo    = (const float*)d_in[8];
  const float* bo    = (const float*)d_in[9];

  char* ws = (char*)d_ws;
  uint16_t* Wib = (uint16_t*)(ws);                  //    262,144 B
  uint16_t* Wcb = (uint16_t*)(ws + 262144);         // 16,777,216 B
  uint16_t* Wob = (uint16_t*)(ws + 17039360);       //    262,144 B
  float*    bc  = (float*)   (ws + 17301504);       //     65,536 B
  // total 17,367,040 bytes

  // ---- pre-pass: convert / combine weights ----
  k_f32_to_bf16<<<128, 256, 0, stream>>>(Wi, Wib, 32768);      // 512*256/4
  k_f32_to_bf16<<<128, 256, 0, stream>>>(Wo, Wob, 32768);      // 256*512/4
  k_combine_w<<<8192, 256, 0, stream>>>(Ws, Wr, Wcb, 2097152); // 2*16*512*512/4
  k_combine_b<<<64, 256, 0, stream>>>(bs, br, bc, 16384);      // 2*16*512

  // ---- fused chain: 256 slabs of 64 tokens ----
  k_fused<<<256, 256, 0, stream>>>(x, route, Wib, bi, Wcb, bc, Wob, bo,
                                   (float*)d_out);
}

// Round 4
// 71.304 us; speedup vs baseline: 1.5227x; 1.5227x over previous
//
#include <hip/hip_runtime.h>
#include <hip/hip_bf16.h>
#include <stdint.h>

// MoEDecoder: B=64,T=256,IN=256,HID=512,OUT=256,L=2,E=16,S=1
// Fused persistent kernel: block = 64-token slab (grid 256), 8 waves (512 thr).
// h lives in ONE LDS buffer (in-place layer update, full-N accumulation).
// Weights staged 2-deep via global_load_lds + counted vmcnt + raw barriers.
// B-tile bank-swizzle: chunk ^= (row>>1)&3, applied on global source AND read.

typedef __attribute__((ext_vector_type(8))) short bf16x8;
typedef __attribute__((ext_vector_type(4))) float f32x4;

#define HPAD 520  // h row stride (elems): 1040B -> 4-bank step -> 2-way (free)
#define VMWAIT(N) asm volatile("s_waitcnt vmcnt(" #N ")" ::: "memory")

static __device__ __forceinline__ uint16_t f2bf(float f) {
  union { float f; uint32_t u; } c; c.f = f;
  uint32_t r = (c.u + 0x7FFFu + ((c.u >> 16) & 1u)) >> 16;
  return (uint16_t)r;
}
static __device__ __forceinline__ float bf2f(uint16_t h) {
  union { uint32_t u; float f; } c; c.u = ((uint32_t)h) << 16;
  return c.f;
}

static __device__ __forceinline__ void glds16(const uint16_t* g, uint16_t* l) {
  __builtin_amdgcn_global_load_lds(
      (const __attribute__((address_space(1))) uint32_t*)g,
      (__attribute__((address_space(3))) uint32_t*)l, 16, 0, 0);
}

__global__ __launch_bounds__(256) void k_f32_to_bf16(
    const float* __restrict__ in, uint16_t* __restrict__ out, int n4) {
  int i = blockIdx.x * 256 + threadIdx.x;
  if (i < n4) {
    float4 v = ((const float4*)in)[i];
    ushort4 o;
    o.x = f2bf(v.x); o.y = f2bf(v.y); o.z = f2bf(v.z); o.w = f2bf(v.w);
    ((ushort4*)out)[i] = o;
  }
}

__global__ __launch_bounds__(256) void k_combine_w(
    const float* __restrict__ Ws, const float* __restrict__ Wr,
    uint16_t* __restrict__ Wc, int n4) {
  int i = blockIdx.x * 256 + threadIdx.x;
  if (i >= n4) return;
  int idx = i * 4;
  int l = idx >> 22;
  int within = idx & (262144 - 1);
  float4 a = *(const float4*)(Ws + l * 262144 + within);
  float4 b = *(const float4*)(Wr + idx);
  ushort4 o;
  o.x = f2bf(a.x + b.x); o.y = f2bf(a.y + b.y);
  o.z = f2bf(a.z + b.z); o.w = f2bf(a.w + b.w);
  ((ushort4*)Wc)[i] = o;
}

__global__ __launch_bounds__(256) void k_combine_b(
    const float* __restrict__ bs, const float* __restrict__ br,
    float* __restrict__ bc, int n) {
  int i = blockIdx.x * 256 + threadIdx.x;
  if (i < n) {
    int l = i >> 13;
    int j = i & 511;
    bc[i] = bs[l * 512 + j] + br[i];
  }
}

// ---- one GEMM phase over the whole N, full-N accumulators ----
// C[64][NT] = h[64][KK] * W[NT][KK]^T (+bias)(+resid)(relu); in-place into h
// unless F32OUT. 8 waves as 2(row) x 4(col); wave tile 32 x NT/4.
// W staged per K-step (BK=32) into lS (2 bufs, NT*32 elems each), 2-deep.
template <int NT, int KK, int RELU, int RESID, int F32OUT>
static __device__ __forceinline__ void gemm_phase(
    const uint16_t* __restrict__ W, const float* __restrict__ bias,
    uint16_t* h, float* __restrict__ gout, uint16_t* lS) {
  constexpr int NSTEP = KK / 32;
  constexpr int LPS = NT / 128;       // glds calls per thread per step
  constexpr int WCOLS = NT / 4;       // 128 or 64
  constexpr int NFRAG = WCOLS / 16;   // 8 or 4

  const int tid = threadIdx.x;
  const int lane = tid & 63, wave = tid >> 6;
  const int wr = wave >> 2, wc = wave & 3;
  const int lr = lane & 15, c0 = lane >> 4;

  // staging: thread t, round j -> LDS row j*128 + t/4, chunk t&3 (16B chunks
  // of the 64B row). Source chunk swizzled: sch = (t&3) ^ ((srow>>1)&3).
  const int srow = tid >> 2;
  const int sch = (tid & 3) ^ ((srow >> 1) & 3);

  auto stage = [&](int buf, int kstep) {
    uint16_t* ldst = lS + buf * (NT * 32) + tid * 8;
    const uint16_t* wsrc = W + kstep * 32 + sch * 8;
    #pragma unroll
    for (int j = 0; j < LPS; j++) {
      int row = j * 128 + srow;
      glds16(wsrc + (size_t)row * KK, ldst + j * 4096);
    }
  };

  f32x4 acc[2][NFRAG];
  #pragma unroll
  for (int m = 0; m < 2; m++)
    #pragma unroll
    for (int n = 0; n < NFRAG; n++) acc[m][n] = (f32x4){0.f, 0.f, 0.f, 0.f};

  stage(0, 0);
  stage(1, 1);

  const uint16_t* pA = h + (size_t)(wr * 32 + lr) * HPAD + c0 * 8;
  const int rowp = wc * WCOLS + lr;                 // B row for frag n=0
  const int bch = c0 ^ ((rowp >> 1) & 3);           // swizzled chunk (n-invar)
  const uint16_t* pB0 = lS + rowp * 32 + bch * 8;

  auto step_body = [&](int t) {
    const int cur = t & 1;
    const uint16_t* pB = pB0 + cur * (NT * 32);
    __builtin_amdgcn_s_barrier();                   // stage data visible
    __builtin_amdgcn_sched_barrier(0);
    const int kb = t * 32;
    bf16x8 a[2], b[NFRAG];
    #pragma unroll
    for (int m = 0; m < 2; m++)
      a[m] = *(const bf16x8*)(pA + (size_t)m * 16 * HPAD + kb);
    #pragma unroll
    for (int n = 0; n < NFRAG; n++)
      b[n] = *(const bf16x8*)(pB + n * 512);        // n*16 rows * 32 elems
    #pragma unroll
    for (int m = 0; m < 2; m++)
      #pragma unroll
      for (int n = 0; n < NFRAG; n++)
        acc[m][n] = __builtin_amdgcn_mfma_f32_16x16x32_bf16(a[m], b[n],
                                                            acc[m][n], 0, 0, 0);
    __builtin_amdgcn_sched_barrier(0);
    __builtin_amdgcn_s_barrier();                   // all reads of cur done
    __builtin_amdgcn_sched_barrier(0);
  };

  for (int t = 0; t < NSTEP - 1; t++) {
    if constexpr (LPS == 4) VMWAIT(4); else VMWAIT(2);  // cur buf landed
    step_body(t);
    if (t + 2 < NSTEP) stage(t & 1, t + 2);         // refill cur for t+2
  }
  VMWAIT(0);
  step_body(NSTEP - 1);

  // epilogue: D frag layout col=lane&15, row=(lane>>4)*4+r
  const int rb = c0 * 4;
  #pragma unroll
  for (int n = 0; n < NFRAG; n++) {
    const int col = wc * WCOLS + n * 16 + lr;
    const float bv = bias[col];
    #pragma unroll
    for (int m = 0; m < 2; m++) {
      #pragma unroll
      for (int r = 0; r < 4; r++) {
        const int row = wr * 32 + m * 16 + rb + r;
        float v = acc[m][n][r] + bv;
        if constexpr (RESID) v += bf2f(h[(size_t)row * HPAD + col]);
        if constexpr (RELU) v = fmaxf(v, 0.0f);
        if constexpr (F32OUT) gout[(size_t)row * 256 + col] = v;
        else h[(size_t)row * HPAD + col] = f2bf(v);
      }
    }
  }
}

__global__ __launch_bounds__(512) void k_fused(
    const float* __restrict__ x, const int* __restrict__ route,
    const uint16_t* __restrict__ Wib, const float* __restrict__ bi,
    const uint16_t* __restrict__ Wcb, const float* __restrict__ bcb,
    const uint16_t* __restrict__ Wob, const float* __restrict__ bo,
    float* __restrict__ out) {
  __shared__ uint16_t h[64 * HPAD];       // 66,560 B
  __shared__ uint16_t lS[2 * 512 * 32];   // 65,536 B   total 132,096 B

  const int tid = threadIdx.x;
  const int bx = blockIdx.x;              // 64-row slab
  const int e = route[bx >> 2];           // 256 rows per batch

  // stage x slab f32 -> bf16 into h (coalesced float4)
  const float* gx = x + (size_t)bx * 16384;
  #pragma unroll
  for (int j = 0; j < 8; j++) {
    int fi = j * 2048 + tid * 4;
    float4 v = *(const float4*)(gx + fi);
    int row = fi >> 8, c = fi & 255;
    ushort4 o;
    o.x = f2bf(v.x); o.y = f2bf(v.y); o.z = f2bf(v.z); o.w = f2bf(v.w);
    *(ushort4*)(h + (size_t)row * HPAD + c) = o;
  }
  __syncthreads();

  // proj: h = relu(x * Wi^T + bi)            N=512 K=256
  gemm_phase<512, 256, 1, 0, 0>(Wib, bi, h, nullptr, lS);
  __syncthreads();
  // layer 0: h = relu(h*Wc[0,e]^T + bc + h)  N=K=512
  gemm_phase<512, 512, 1, 1, 0>(Wcb + (size_t)e * 262144, bcb + e * 512,
                                h, nullptr, lS);
  __syncthreads();
  // layer 1
  gemm_phase<512, 512, 1, 1, 0>(Wcb + (size_t)(16 + e) * 262144,
                                bcb + (16 + e) * 512, h, nullptr, lS);
  __syncthreads();
  // out: f32 = h * Wo^T + bo                 N=256 K=512
  gemm_phase<256, 512, 0, 0, 1>(Wob, bo, h, out + (size_t)bx * 16384, lS);
}

extern "C" void kernel_launch(void* const* d_in, const int* in_sizes, int n_in,
                              void* d_out, int out_size, void* d_ws, size_t ws_size,
                              hipStream_t stream) {
  const float* x     = (const float*)d_in[0];
  const int*   route = (const int*)d_in[1];
  const float* Wi    = (const float*)d_in[2];
  const float* bi    = (const float*)d_in[3];
  const float* Wr    = (const float*)d_in[4];
  const float* br    = (const float*)d_in[5];
  const float* Ws    = (const float*)d_in[6];
  const float* bs    = (const float*)d_in[7];
  const float* Wo    = (const float*)d_in[8];
  const float* bo    = (const float*)d_in[9];

  char* ws = (char*)d_ws;
  uint16_t* Wib = (uint16_t*)(ws);                  //    262,144 B
  uint16_t* Wcb = (uint16_t*)(ws + 262144);         // 16,777,216 B
  uint16_t* Wob = (uint16_t*)(ws + 17039360);       //    262,144 B
  float*    bc  = (float*)   (ws + 17301504);       //     65,536 B

  k_f32_to_bf16<<<128, 256, 0, stream>>>(Wi, Wib, 32768);
  k_f32_to_bf16<<<128, 256, 0, stream>>>(Wo, Wob, 32768);
  k_combine_w<<<8192, 256, 0, stream>>>(Ws, Wr, Wcb, 2097152);
  k_combine_b<<<64, 256, 0, stream>>>(bs, br, bc, 16384);

  k_fused<<<256, 512, 0, stream>>>(x, route, Wib, bi, Wcb, bc, Wob, bo,
                                   (float*)d_out);
}

// Round 5
// 50.242 us; speedup vs baseline: 2.1610x; 1.4192x over previous
//
#include <hip/hip_runtime.h>
#include <hip/hip_bf16.h>
#include <stdint.h>

// MoEDecoder: B=64,T=256,IN=256,HID=512,OUT=256,L=2,E=16,S=1
// Fused persistent kernel, barrier-free K-loops:
//   block = 64-token slab (512 thr, 8 waves as 1x8), h in LDS (in-place),
//   each wave stages ITS OWN 64 W-rows (private LDS dbuf, counted vmcnt),
//   reg-double-buffered fragments, bias+resid folded into acc init,
//   XCD-aware block swizzle (8 whole batches per XCD => weights L2-fit).

typedef __attribute__((ext_vector_type(8))) short bf16x8;
typedef __attribute__((ext_vector_type(4))) float f32x4;

#define HPAD 520  // h row stride (elems): 1040B -> 2-way bank alias (free)
#define VMWAIT(N) asm volatile("s_waitcnt vmcnt(" #N ")" ::: "memory")

static __device__ __forceinline__ uint16_t f2bf(float f) {
  union { float f; uint32_t u; } c; c.f = f;
  uint32_t r = (c.u + 0x7FFFu + ((c.u >> 16) & 1u)) >> 16;
  return (uint16_t)r;
}
static __device__ __forceinline__ float bf2f(uint16_t h) {
  union { uint32_t u; float f; } c; c.u = ((uint32_t)h) << 16;
  return c.f;
}

static __device__ __forceinline__ void glds16(const uint16_t* g, uint16_t* l) {
  __builtin_amdgcn_global_load_lds(
      (const __attribute__((address_space(1))) uint32_t*)g,
      (__attribute__((address_space(3))) uint32_t*)l, 16, 0, 0);
}

// ---- merged pre-pass: Wc=Ws+Wr (bf16), Wi/Wo bf16, bc=bs+br ----
__global__ __launch_bounds__(256) void k_prep(
    const float* __restrict__ Ws, const float* __restrict__ Wr,
    const float* __restrict__ Wi, const float* __restrict__ Wo,
    const float* __restrict__ bs, const float* __restrict__ br,
    uint16_t* __restrict__ Wcb, uint16_t* __restrict__ Wib,
    uint16_t* __restrict__ Wob, float* __restrict__ bc) {
  int bid = blockIdx.x, tid = threadIdx.x;
  if (bid < 8192) {                       // combine_w: 2*16*512*512 / 4
    int i = bid * 256 + tid;
    int idx = i * 4;
    int l = idx >> 22;
    int within = idx & (262144 - 1);
    float4 a = *(const float4*)(Ws + l * 262144 + within);
    float4 b = *(const float4*)(Wr + idx);
    ushort4 o;
    o.x = f2bf(a.x + b.x); o.y = f2bf(a.y + b.y);
    o.z = f2bf(a.z + b.z); o.w = f2bf(a.w + b.w);
    ((ushort4*)Wcb)[i] = o;
  } else if (bid < 8320) {                // Wi: 512*256/4
    int i = (bid - 8192) * 256 + tid;
    float4 v = ((const float4*)Wi)[i];
    ushort4 o;
    o.x = f2bf(v.x); o.y = f2bf(v.y); o.z = f2bf(v.z); o.w = f2bf(v.w);
    ((ushort4*)Wib)[i] = o;
  } else if (bid < 8448) {                // Wo: 256*512/4
    int i = (bid - 8320) * 256 + tid;
    float4 v = ((const float4*)Wo)[i];
    ushort4 o;
    o.x = f2bf(v.x); o.y = f2bf(v.y); o.z = f2bf(v.z); o.w = f2bf(v.w);
    ((ushort4*)Wob)[i] = o;
  } else {                                // bc: 2*16*512
    int i = (bid - 8448) * 256 + tid;
    int l = i >> 13, j = i & 511;
    bc[i] = bs[l * 512 + j] + br[i];
  }
}

// ---- one GEMM phase, barrier-free K-loop ----
// C[64][NT] = h[64][KK] * W[NT][KK]^T (+bias)(+resid)(relu), in-place into h
// unless F32OUT. 8 waves, wave w owns cols [w*NC, w*NC+NC), all 64 rows.
// Wave stages its own W rows into private LDS region (2 bufs, counted vmcnt).
template <int NT, int KK, int RESID, int F32OUT>
static __device__ __forceinline__ void gemm_phase(
    const uint16_t* __restrict__ W, const float* __restrict__ bias,
    uint16_t* h, float* __restrict__ gout, uint16_t* lS) {
  constexpr int NSTEP = KK / 32;
  constexpr int NC = NT / 8;          // 64 or 32 cols per wave
  constexpr int NFRAG = NC / 16;      // 4 or 2
  constexpr int LPS = NFRAG;          // glds per stage (1KB each)

  const int tid = threadIdx.x;
  const int lane = tid & 63, wave = tid >> 6;
  const int lr = lane & 15, c0 = lane >> 4;

  uint16_t* lw = lS + wave * 4096;    // private 8KB region (2 x 4KB bufs)

  // staging: lane l covers local row j*16 + l/4, 16B chunk (l&3), source
  // chunk XOR-swizzled so ds_read side is conflict-free (verified R4).
  const int srow = lane >> 2;
  const int sch = (lane & 3) ^ ((lane >> 3) & 3);
  const uint16_t* wbase = W + (size_t)(wave * NC + srow) * KK + sch * 8;

  auto stage = [&](int buf, int t) {
    #pragma unroll
    for (int j = 0; j < LPS; j++)
      glds16(wbase + (size_t)j * 16 * KK + t * 32,
             lw + buf * (NC * 32) + j * 512);
  };

  // ---- acc init = bias (+ residual) : hidden under first stage latency ----
  const int rb = c0 * 4;
  f32x4 acc[4][NFRAG];
  stage(0, 0);
  stage(1, 1);
  #pragma unroll
  for (int n = 0; n < NFRAG; n++) {
    const int col = wave * NC + n * 16 + lr;
    const float bv = bias[col];
    #pragma unroll
    for (int m = 0; m < 4; m++)
      #pragma unroll
      for (int r = 0; r < 4; r++) {
        float v = bv;
        if constexpr (RESID)
          v += bf2f(h[(size_t)(m * 16 + rb + r) * HPAD + col]);
        acc[m][n][r] = v;
      }
  }

  const int bch = c0 ^ ((lr >> 1) & 3);
  const uint16_t* pB0 = lw + lr * 32 + bch * 8;
  const uint16_t* pA0 = h + (size_t)lr * HPAD + c0 * 8;

  bf16x8 a[2][4], b[2][NFRAG];

  if constexpr (LPS == 4) { VMWAIT(4); } else { VMWAIT(2); }  // stage(0) done
  #pragma unroll
  for (int m = 0; m < 4; m++)
    a[0][m] = *(const bf16x8*)(pA0 + (size_t)m * 16 * HPAD);
  #pragma unroll
  for (int n = 0; n < NFRAG; n++)
    b[0][n] = *(const bf16x8*)(pB0 + n * 512);

  #pragma unroll
  for (int t = 0; t < NSTEP; t++) {
    const int pp = t & 1;
    // refill just-freed buf (its data already lives in regs a[pp]/b[pp])
    if (t + 2 < NSTEP) stage(pp, t + 2);
    if (t + 1 < NSTEP) {
      if (t + 2 < NSTEP) {
        if constexpr (LPS == 4) { VMWAIT(4); } else { VMWAIT(2); }
      } else {
        VMWAIT(0);
      }
      const uint16_t* pBn = pB0 + ((t + 1) & 1) * (NC * 32);
      #pragma unroll
      for (int m = 0; m < 4; m++)
        a[pp ^ 1][m] =
            *(const bf16x8*)(pA0 + (size_t)m * 16 * HPAD + (t + 1) * 32);
      #pragma unroll
      for (int n = 0; n < NFRAG; n++)
        b[pp ^ 1][n] = *(const bf16x8*)(pBn + n * 512);
    }
    #pragma unroll
    for (int m = 0; m < 4; m++)
      #pragma unroll
      for (int n = 0; n < NFRAG; n++)
        acc[m][n] = __builtin_amdgcn_mfma_f32_16x16x32_bf16(
            a[pp][m], b[pp][n], acc[m][n], 0, 0, 0);
  }

  // ---- epilogue ----
  if constexpr (F32OUT) {
    #pragma unroll
    for (int n = 0; n < NFRAG; n++) {
      const int col = wave * NC + n * 16 + lr;
      #pragma unroll
      for (int m = 0; m < 4; m++)
        #pragma unroll
        for (int r = 0; r < 4; r++)
          gout[(size_t)(m * 16 + rb + r) * 256 + col] = acc[m][n][r];
    }
  } else {
    __syncthreads();  // all waves done reading h (A + resid)
    #pragma unroll
    for (int n = 0; n < NFRAG; n++) {
      const int col = wave * NC + n * 16 + lr;
      #pragma unroll
      for (int m = 0; m < 4; m++)
        #pragma unroll
        for (int r = 0; r < 4; r++)
          h[(size_t)(m * 16 + rb + r) * HPAD + col] =
              f2bf(fmaxf(acc[m][n][r], 0.0f));
    }
    __syncthreads();  // writes visible before next phase reads
  }
}

__global__ __launch_bounds__(512) void k_fused(
    const float* __restrict__ x, const int* __restrict__ route,
    const uint16_t* __restrict__ Wib, const float* __restrict__ bi,
    const uint16_t* __restrict__ Wcb, const float* __restrict__ bcb,
    const uint16_t* __restrict__ Wob, const float* __restrict__ bo,
    float* __restrict__ out) {
  __shared__ uint16_t h[64 * HPAD];     // 66,560 B
  __shared__ uint16_t lS[8 * 4096];     // 65,536 B   total 132,096 B

  const int tid = threadIdx.x;
  // XCD swizzle: dispatch round-robins XCD = bid%8. Give XCD r the 8 batches
  // with batch%8==r (4 slabs each) -> per-phase L2 weight set <= 4MB (fits).
  const int bid = blockIdx.x;
  const int r = bid & 7, q = bid >> 3;
  const int batch = (q >> 2) * 8 + r;   // 0..63
  const int bx = batch * 4 + (q & 3);   // slab id 0..255
  const int e = route[batch];

  // stage x slab f32 -> bf16 into h (coalesced float4)
  const float* gx = x + (size_t)bx * 16384;
  #pragma unroll
  for (int j = 0; j < 8; j++) {
    int fi = j * 2048 + tid * 4;
    float4 v = *(const float4*)(gx + fi);
    int row = fi >> 8, c = fi & 255;
    ushort4 o;
    o.x = f2bf(v.x); o.y = f2bf(v.y); o.z = f2bf(v.z); o.w = f2bf(v.w);
    *(ushort4*)(h + (size_t)row * HPAD + c) = o;
  }
  __syncthreads();

  // proj: h = relu(x * Wi^T + bi)            N=512 K=256
  gemm_phase<512, 256, 0, 0>(Wib, bi, h, nullptr, lS);
  // layer 0: h = relu(h*Wc[0,e]^T + bc + h)  N=K=512
  gemm_phase<512, 512, 1, 0>(Wcb + (size_t)e * 262144, bcb + e * 512,
                             h, nullptr, lS);
  // layer 1
  gemm_phase<512, 512, 1, 0>(Wcb + (size_t)(16 + e) * 262144,
                             bcb + (16 + e) * 512, h, nullptr, lS);
  // out: f32 = h * Wo^T + bo                 N=256 K=512
  gemm_phase<256, 512, 0, 1>(Wob, bo, h, out + (size_t)bx * 16384, lS);
}

extern "C" void kernel_launch(void* const* d_in, const int* in_sizes, int n_in,
                              void* d_out, int out_size, void* d_ws, size_t ws_size,
                              hipStream_t stream) {
  const float* x     = (const float*)d_in[0];
  const int*   route = (const int*)d_in[1];
  const float* Wi    = (const float*)d_in[2];
  const float* bi    = (const float*)d_in[3];
  const float* Wr    = (const float*)d_in[4];
  const float* br    = (const float*)d_in[5];
  const float* Ws    = (const float*)d_in[6];
  const float* bs    = (const float*)d_in[7];
  const float* Wo    = (const float*)d_in[8];
  const float* bo    = (const float*)d_in[9];

  char* ws = (char*)d_ws;
  uint16_t* Wib = (uint16_t*)(ws);                  //    262,144 B
  uint16_t* Wcb = (uint16_t*)(ws + 262144);         // 16,777,216 B
  uint16_t* Wob = (uint16_t*)(ws + 17039360);       //    262,144 B
  float*    bc  = (float*)   (ws + 17301504);       //     65,536 B

  k_prep<<<8512, 256, 0, stream>>>(Ws, Wr, Wi, Wo, bs, br,
                                   Wcb, Wib, Wob, bc);
  k_fused<<<256, 512, 0, stream>>>(x, route, Wib, bi, Wcb, bc, Wob, bo,
                                   (float*)d_out);
}